// Round 4
// baseline (644.167 us; speedup 1.0000x reference)
//
#include <hip/hip_runtime.h>

// ---------------------------------------------------------------------------
// GAT encoder: x --GATConv(2 heads,128)--> ELU --> {GATConv mu, GATConv ls}
// N=50000, E=800000 (+self loops). fp32 in/out (round-3 finding). Edges int32
// with device-side int64 auto-detect. CSR by dst once per call; atomic-free
// aggregation. Round 4: GEMM rewritten 64x256 tile, 8x8 per thread, BK=32
// (FMA:LDS ratio 4x better; was VALUBusy 44% at 146us/dispatch).
// ---------------------------------------------------------------------------

typedef unsigned short u16;
typedef unsigned int u32;

__device__ __forceinline__ void unpack2(u32 u, float& lo, float& hi) {
    union { u32 i; float f; } a, b;
    a.i = u << 16; b.i = u & 0xffff0000u;
    lo = a.f; hi = b.f;
}
__device__ __forceinline__ u16 f2b(float f) {  // RNE float->bf16
    union { float f; u32 i; } v; v.f = f;
    u32 x = v.i;
    return (u16)((x + 0x7fffu + ((x >> 16) & 1u)) >> 16);
}
__device__ __forceinline__ float4 loadh4(const float* __restrict__ p, size_t i) {
    return *(const float4*)(p + i);
}
__device__ __forceinline__ float4 loadh4(const u16* __restrict__ p, size_t i) {
    uint2 u = *(const uint2*)(p + i);
    float4 r;
    unpack2(u.x, r.x, r.y);
    unpack2(u.y, r.z, r.w);
    return r;
}
__device__ __forceinline__ void storeh4(float* __restrict__ p, size_t i, float4 v) {
    *(float4*)(p + i) = v;
}
__device__ __forceinline__ void storeh4(u16* __restrict__ p, size_t i, float4 v) {
    uint2 pk = make_uint2((u32)f2b(v.x) | ((u32)f2b(v.y) << 16),
                          (u32)f2b(v.z) | ((u32)f2b(v.w) << 16));
    *(uint2*)(p + i) = pk;
}

// ---------------- edge dtype detect + normalize ----------------
__global__ __launch_bounds__(256) void k_detect(const u32* __restrict__ ebuf,
                                                int* __restrict__ flag) {
    __shared__ int nz;
    if (threadIdx.x == 0) nz = 0;
    __syncthreads();
    if (ebuf[2 * threadIdx.x + 1] != 0u) atomicAdd(&nz, 1);
    __syncthreads();
    if (threadIdx.x == 0) *flag = (nz == 0) ? 1 : 0;
}

__global__ __launch_bounds__(256) void k_extract(const u32* __restrict__ ebuf, int E,
                                                 const int* __restrict__ flag,
                                                 int* __restrict__ se,
                                                 int* __restrict__ de) {
    int e = blockIdx.x * 256 + threadIdx.x;
    if (e >= E) return;
    if (*flag) {  // int64 layout
        se[e] = (int)ebuf[2 * (size_t)e];
        de[e] = (int)ebuf[2 * ((size_t)E + (size_t)e)];
    } else {  // int32 layout
        se[e] = (int)ebuf[e];
        de[e] = (int)ebuf[(size_t)E + (size_t)e];
    }
}

// ---------------- CSR build ----------------
__global__ __launch_bounds__(256) void k_count(const int* __restrict__ dst, int E,
                                               int* __restrict__ deg) {
    int e = blockIdx.x * 256 + threadIdx.x;
    if (e < E) atomicAdd(&deg[dst[e]], 1);
}

__global__ __launch_bounds__(256) void k_scan_a(const int* __restrict__ deg, int n,
                                                int* __restrict__ bsum) {
    __shared__ int s[256];
    int i = blockIdx.x * 256 + threadIdx.x;
    s[threadIdx.x] = (i < n) ? deg[i] : 0;
    __syncthreads();
    for (int st = 128; st > 0; st >>= 1) {
        if (threadIdx.x < st) s[threadIdx.x] += s[threadIdx.x + st];
        __syncthreads();
    }
    if (threadIdx.x == 0) bsum[blockIdx.x] = s[0];
}

__global__ __launch_bounds__(256) void k_scan_b(int* __restrict__ bsum, int nb) {
    __shared__ int s[256];
    int t = threadIdx.x;
    int v = (t < nb) ? bsum[t] : 0;
    s[t] = v;
    __syncthreads();
    for (int off = 1; off < 256; off <<= 1) {
        int add = (t >= off) ? s[t - off] : 0;
        __syncthreads();
        s[t] += add;
        __syncthreads();
    }
    if (t < nb) bsum[t] = s[t] - v;  // exclusive
}

__global__ __launch_bounds__(256) void k_scan_c(const int* __restrict__ deg, int n,
                                                const int* __restrict__ bsum,
                                                int* __restrict__ rowptr,
                                                int* __restrict__ cursor, int E) {
    __shared__ int s[256];
    int t = threadIdx.x;
    int i = blockIdx.x * 256 + t;
    int v = (i < n) ? deg[i] : 0;
    s[t] = v;
    __syncthreads();
    for (int off = 1; off < 256; off <<= 1) {
        int add = (t >= off) ? s[t - off] : 0;
        __syncthreads();
        s[t] += add;
        __syncthreads();
    }
    if (i < n) {
        int ex = bsum[blockIdx.x] + s[t] - v;
        rowptr[i] = ex;
        cursor[i] = ex;
    }
    if (i == 0) rowptr[n] = E;
}

__global__ __launch_bounds__(256) void k_fill(const int* __restrict__ src,
                                              const int* __restrict__ dst, int E,
                                              int* __restrict__ cursor,
                                              int* __restrict__ csr_src) {
    int e = blockIdx.x * 256 + threadIdx.x;
    if (e < E) {
        int d = dst[e];
        int slot = atomicAdd(&cursor[d], 1);
        csr_src[slot] = src[e];
    }
}

// ---------------- GEMM: out[M,256] = A[M,K](f32) @ W[K,256](f32) ------------
// split==256: single W (row stride 256). split==128: cols 0..127 from Wl,
// 128..255 from Wr (row stride 128 each). 256 thr; 64-row x 256-col tile,
// BK=32 chunks. Thread: 8 rows (rg=(tid>>5)*8) x 8 cols (cg=(tid&31)*4 and
// cg+128). All ds_read_b128 lane-contiguous (W) or half-wave broadcast (A).
template <int K, typename OT>
__global__ __launch_bounds__(256) void k_gemm(const float* __restrict__ A,
                                              const float* __restrict__ Wl,
                                              const float* __restrict__ Wr, int split,
                                              OT* __restrict__ out, int M) {
    __shared__ float As[64 * 32];   // 8KB
    __shared__ float Ws[32 * 256];  // 32KB
    const int tid = threadIdx.x;
    const int row0 = blockIdx.x * 64;

    float acc[8][8];
#pragma unroll
    for (int r = 0; r < 8; r++)
#pragma unroll
        for (int c = 0; c < 8; c++) acc[r][c] = 0.f;

    const int cg = (tid & 31) * 4;   // cols cg..cg+3 and cg+128..cg+131
    const int rg = (tid >> 5) * 8;   // rows rg..rg+7

    for (int kc = 0; kc < K; kc += 32) {
        __syncthreads();  // prior chunk's LDS reads done
        // stage A chunk: 64 rows x 32 k = 512 float4, 2 per thread
#pragma unroll
        for (int i = 0; i < 2; i++) {
            int f = tid + i * 256;
            int r = f >> 3, k4 = (f & 7) * 4;
            float4 val = make_float4(0.f, 0.f, 0.f, 0.f);
            if (row0 + r < M)
                val = *(const float4*)(A + (size_t)(row0 + r) * K + kc + k4);
            *(float4*)(&As[r * 32 + k4]) = val;
        }
        // stage W chunk: 32 k x 256 cols = 2048 float4, 8 per thread
#pragma unroll
        for (int i = 0; i < 8; i++) {
            int f = tid + i * 256;
            int k = f >> 6, c = (f & 63) * 4;
            const float* wp;
            if (split == 256)
                wp = Wl + (size_t)(kc + k) * 256 + c;
            else
                wp = (c < 128) ? Wl + (size_t)(kc + k) * 128 + c
                               : Wr + (size_t)(kc + k) * 128 + (c - 128);
            *(float4*)(&Ws[k * 256 + c]) = *(const float4*)wp;
        }
        __syncthreads();
        // compute: 8 k4-steps of 4 k each
#pragma unroll
        for (int k4 = 0; k4 < 32; k4 += 4) {
            float4 wv[4][2];
#pragma unroll
            for (int j = 0; j < 4; j++) {
                wv[j][0] = *(const float4*)(&Ws[(k4 + j) * 256 + cg]);
                wv[j][1] = *(const float4*)(&Ws[(k4 + j) * 256 + cg + 128]);
            }
#pragma unroll
            for (int r = 0; r < 8; r++) {
                float4 a = *(const float4*)(&As[(rg + r) * 32 + k4]);
                float av[4] = {a.x, a.y, a.z, a.w};
#pragma unroll
                for (int j = 0; j < 4; j++) {
                    acc[r][0] += av[j] * wv[j][0].x;
                    acc[r][1] += av[j] * wv[j][0].y;
                    acc[r][2] += av[j] * wv[j][0].z;
                    acc[r][3] += av[j] * wv[j][0].w;
                    acc[r][4] += av[j] * wv[j][1].x;
                    acc[r][5] += av[j] * wv[j][1].y;
                    acc[r][6] += av[j] * wv[j][1].z;
                    acc[r][7] += av[j] * wv[j][1].w;
                }
            }
        }
    }

#pragma unroll
    for (int r = 0; r < 8; r++) {
        int row = row0 + rg + r;
        if (row < M) {
            storeh4(out, (size_t)row * 256 + cg,
                    make_float4(acc[r][0], acc[r][1], acc[r][2], acc[r][3]));
            storeh4(out, (size_t)row * 256 + cg + 128,
                    make_float4(acc[r][4], acc[r][5], acc[r][6], acc[r][7]));
        }
    }
}

// ---------------- attention logits: as/ad[n,NS] ------------------------------
// One wave per node; lane l owns channels 4l..4l+3 of h[n,256].
// LOGW=5: 2 slots of 128 ch (layer 1). LOGW=4: 4 slots of 64 ch (mu|ls).
template <int LOGW, typename HT>
__global__ __launch_bounds__(256) void k_alphas(const HT* __restrict__ h,
                                                const float* __restrict__ as_lo,
                                                const float* __restrict__ as_hi,
                                                const float* __restrict__ ad_lo,
                                                const float* __restrict__ ad_hi,
                                                float* __restrict__ as_out,
                                                float* __restrict__ ad_out, int n) {
    const int W = 1 << LOGW;
    const int NS = 64 >> LOGW;
    int wid = blockIdx.x * 4 + (threadIdx.x >> 6);
    int lane = threadIdx.x & 63;
    if (wid >= n) return;
    int c = lane * 4;
    int ci = c & 127;
    const float* ap = (c < 128) ? as_lo : as_hi;
    const float* dp = (c < 128) ? ad_lo : ad_hi;
    float4 hv = loadh4(h, (size_t)wid * 256 + c);
    float4 av = *(const float4*)(ap + ci);
    float4 dv = *(const float4*)(dp + ci);
    float ssum = hv.x * av.x + hv.y * av.y + hv.z * av.z + hv.w * av.w;
    float dsum = hv.x * dv.x + hv.y * dv.y + hv.z * dv.z + hv.w * dv.w;
#pragma unroll
    for (int m = W / 2; m >= 1; m >>= 1) {
        ssum += __shfl_xor(ssum, m, 64);
        dsum += __shfl_xor(dsum, m, 64);
    }
    if ((lane & (W - 1)) == 0) {
        int slot = lane >> LOGW;
        as_out[(size_t)wid * NS + slot] = ssum;
        ad_out[(size_t)wid * NS + slot] = dsum;
    }
}

// ---------------- aggregation (softmax-weighted gather) ----------------------
// One wave per dst node; lane owns 4 channels; self-loop folded in.
// MODE 0: +bias, ELU, write fp32 x1 [n,256]. MODE 1: +bias, write mu/ls.
template <int LOGW, int MODE, typename HT>
__global__ __launch_bounds__(256) void k_agg(const HT* __restrict__ h,
                                             const int* __restrict__ rowptr,
                                             const int* __restrict__ csr_src,
                                             const float* __restrict__ as,
                                             const float* __restrict__ ad,
                                             const float* __restrict__ b_lo,
                                             const float* __restrict__ b_hi,
                                             float* __restrict__ outp, int n) {
    const int NS = 64 >> LOGW;
    int wid = blockIdx.x * 4 + (threadIdx.x >> 6);
    int lane = threadIdx.x & 63;
    if (wid >= n) return;
    int slot = lane >> LOGW;
    int c = lane * 4;

    float adv = ad[(size_t)wid * NS + slot];
    float e = as[(size_t)wid * NS + slot] + adv;  // self-loop
    e = fmaxf(e, 0.2f * e);                       // LeakyReLU(0.2)
    float w = __expf(e);
    float denom = w;
    float4 hv = loadh4(h, (size_t)wid * 256 + c);
    float acc0 = w * hv.x, acc1 = w * hv.y, acc2 = w * hv.z, acc3 = w * hv.w;

    int rb = rowptr[wid], re = rowptr[wid + 1];
    for (int p = rb; p < re; ++p) {
        int s = csr_src[p];
        float ev = as[(size_t)s * NS + slot] + adv;
        ev = fmaxf(ev, 0.2f * ev);
        float ww = __expf(ev);
        denom += ww;
        float4 hh = loadh4(h, (size_t)s * 256 + c);
        acc0 += ww * hh.x;
        acc1 += ww * hh.y;
        acc2 += ww * hh.z;
        acc3 += ww * hh.w;
    }
    float inv = 1.0f / (denom + 1e-16f);

    int ci = c & 127;
    const float* bp = (c < 128) ? b_lo : b_hi;
    float4 bv = *(const float4*)(bp + ci);
    float v0 = acc0 * inv + bv.x;
    float v1 = acc1 * inv + bv.y;
    float v2 = acc2 * inv + bv.z;
    float v3 = acc3 * inv + bv.w;

    if (MODE == 0) {  // ELU -> x1 fp32 [n,256]
        v0 = v0 > 0.f ? v0 : expm1f(v0);
        v1 = v1 > 0.f ? v1 : expm1f(v1);
        v2 = v2 > 0.f ? v2 : expm1f(v2);
        v3 = v3 > 0.f ? v3 : expm1f(v3);
        *(float4*)(&outp[(size_t)wid * 256 + c]) = make_float4(v0, v1, v2, v3);
    } else {  // mu (c<128) then logstd, each [n,128] fp32, concatenated
        size_t base = (c < 128) ? ((size_t)wid * 128 + c)
                                : ((size_t)n * 128 + (size_t)wid * 128 + (c - 128));
        *(float4*)(&outp[base]) = make_float4(v0, v1, v2, v3);
    }
}

// ---------------------------------------------------------------------------
extern "C" void kernel_launch(void* const* d_in, const int* in_sizes, int n_in,
                              void* d_out, int out_size, void* d_ws, size_t ws_size,
                              hipStream_t stream) {
    const float* x = (const float*)d_in[0];
    const u32* ebuf = (const u32*)d_in[1];
    const float* W1 = (const float*)d_in[2];
    const float* a_src1 = (const float*)d_in[3];
    const float* a_dst1 = (const float*)d_in[4];
    const float* b1 = (const float*)d_in[5];
    const float* W_mu = (const float*)d_in[6];
    const float* a_src_mu = (const float*)d_in[7];
    const float* a_dst_mu = (const float*)d_in[8];
    const float* b_mu = (const float*)d_in[9];
    const float* W_ls = (const float*)d_in[10];
    const float* a_src_ls = (const float*)d_in[11];
    const float* a_dst_ls = (const float*)d_in[12];
    const float* b_ls = (const float*)d_in[13];

    const int n = in_sizes[0] / 128;  // 50000
    const int E = in_sizes[1] / 2;    // 800000

    char* base = (char*)d_ws;
    size_t off = 0;
    auto alloc = [&](size_t b) -> char* {
        char* p = base + off;
        off = (off + b + 255) & ~(size_t)255;
        return p;
    };
    int* rowptr = (int*)alloc((size_t)(n + 1) * 4);
    int* cursor = (int*)alloc((size_t)n * 4);
    int* csr = (int*)alloc((size_t)E * 4);
    int* bsum = (int*)alloc(256 * 4);
    int* eflag = (int*)alloc(256);
    int* se = (int*)alloc((size_t)E * 4);
    int* de = (int*)alloc((size_t)E * 4);
    float* as = (float*)alloc((size_t)n * 4 * 4);
    float* ad = (float*)alloc((size_t)n * 4 * 4);
    char* hraw = alloc(0);  // h last; fp32 if it fits, else bf16
    bool hf32 = (off + (size_t)n * 256 * 4) <= ws_size;
    float* hf = (float*)hraw;
    u16* hb = (u16*)hraw;
    float* x1 = (float*)d_out;  // n*256 fp32 scratch; dead before final writes

    const int nb = (n + 255) / 256;
    const int eg = (E + 255) / 256;
    const int ng4 = (n + 3) / 4;
    const int gg = (n + 63) / 64;

    // edge normalize + CSR build (reused by all three convs)
    k_detect<<<1, 256, 0, stream>>>(ebuf, eflag);
    k_extract<<<eg, 256, 0, stream>>>(ebuf, E, eflag, se, de);
    hipMemsetAsync(cursor, 0, (size_t)n * 4, stream);
    k_count<<<eg, 256, 0, stream>>>(de, E, cursor);
    k_scan_a<<<nb, 256, 0, stream>>>(cursor, n, bsum);
    k_scan_b<<<1, 256, 0, stream>>>(bsum, nb);
    k_scan_c<<<nb, 256, 0, stream>>>(cursor, n, bsum, rowptr, cursor, E);
    k_fill<<<eg, 256, 0, stream>>>(se, de, E, cursor, csr);

    if (hf32) {
        k_gemm<128, float><<<gg, 256, 0, stream>>>(x, W1, W1, 256, hf, n);
        k_alphas<5, float><<<ng4, 256, 0, stream>>>(hf, a_src1, a_src1 + 128, a_dst1,
                                                    a_dst1 + 128, as, ad, n);
        k_agg<5, 0, float><<<ng4, 256, 0, stream>>>(hf, rowptr, csr, as, ad, b1,
                                                    b1 + 128, x1, n);
        k_gemm<256, float><<<gg, 256, 0, stream>>>(x1, W_mu, W_ls, 128, hf, n);
        k_alphas<4, float><<<ng4, 256, 0, stream>>>(hf, a_src_mu, a_src_ls, a_dst_mu,
                                                    a_dst_ls, as, ad, n);
        k_agg<4, 1, float><<<ng4, 256, 0, stream>>>(hf, rowptr, csr, as, ad, b_mu,
                                                    b_ls, (float*)d_out, n);
    } else {
        k_gemm<128, u16><<<gg, 256, 0, stream>>>(x, W1, W1, 256, hb, n);
        k_alphas<5, u16><<<ng4, 256, 0, stream>>>(hb, a_src1, a_src1 + 128, a_dst1,
                                                  a_dst1 + 128, as, ad, n);
        k_agg<5, 0, u16><<<ng4, 256, 0, stream>>>(hb, rowptr, csr, as, ad, b1,
                                                  b1 + 128, x1, n);
        k_gemm<256, u16><<<gg, 256, 0, stream>>>(x1, W_mu, W_ls, 128, hb, n);
        k_alphas<4, u16><<<ng4, 256, 0, stream>>>(hb, a_src_mu, a_src_ls, a_dst_mu,
                                                  a_dst_ls, as, ad, n);
        k_agg<4, 1, u16><<<ng4, 256, 0, stream>>>(hb, rowptr, csr, as, ad, b_mu,
                                                  b_ls, (float*)d_out, n);
    }
}

// Round 5
// 601.801 us; speedup vs baseline: 1.0704x; 1.0704x over previous
//
#include <hip/hip_runtime.h>
#include <hip/hip_fp16.h>

// ---------------------------------------------------------------------------
// GAT encoder: x --GATConv(2 heads,128)--> ELU --> {GATConv mu, GATConv ls}
// N=50000, E=800000 (+self loops). fp32 in/out. Edges int32 w/ int64 detect.
// Round 5: h stored fp16 (halves k_agg's 430MB L2-fill gather traffic, the
// measured bottleneck: 8.4x XCD amplification). Attention logits fused into
// the GEMM epilogue from fp32 accumulators (precision + kills k_alphas).
// x1 scratch (fp32 [n,256]) lives in d_out (dead before final agg writes).
// ---------------------------------------------------------------------------

typedef unsigned short u16;
typedef unsigned int u32;

__device__ __forceinline__ float4 loadh4(const u16* __restrict__ p, size_t i) {
    union { uint2 u; __half h[4]; } t;
    t.u = *(const uint2*)(p + i);
    return make_float4(__half2float(t.h[0]), __half2float(t.h[1]),
                       __half2float(t.h[2]), __half2float(t.h[3]));
}
__device__ __forceinline__ void storeh4(u16* __restrict__ p, size_t i, float4 v) {
    union { uint2 u; __half h[4]; } t;
    t.h[0] = __float2half_rn(v.x);
    t.h[1] = __float2half_rn(v.y);
    t.h[2] = __float2half_rn(v.z);
    t.h[3] = __float2half_rn(v.w);
    *(uint2*)(p + i) = t.u;
}

// ---------------- edge dtype detect + normalize ----------------
__global__ __launch_bounds__(256) void k_detect(const u32* __restrict__ ebuf,
                                                int* __restrict__ flag) {
    __shared__ int nz;
    if (threadIdx.x == 0) nz = 0;
    __syncthreads();
    if (ebuf[2 * threadIdx.x + 1] != 0u) atomicAdd(&nz, 1);
    __syncthreads();
    if (threadIdx.x == 0) *flag = (nz == 0) ? 1 : 0;
}

__global__ __launch_bounds__(256) void k_extract(const u32* __restrict__ ebuf, int E,
                                                 const int* __restrict__ flag,
                                                 int* __restrict__ se,
                                                 int* __restrict__ de) {
    int e = blockIdx.x * 256 + threadIdx.x;
    if (e >= E) return;
    if (*flag) {  // int64 layout
        se[e] = (int)ebuf[2 * (size_t)e];
        de[e] = (int)ebuf[2 * ((size_t)E + (size_t)e)];
    } else {  // int32 layout
        se[e] = (int)ebuf[e];
        de[e] = (int)ebuf[(size_t)E + (size_t)e];
    }
}

// ---------------- CSR build ----------------
__global__ __launch_bounds__(256) void k_count(const int* __restrict__ dst, int E,
                                               int* __restrict__ deg) {
    int e = blockIdx.x * 256 + threadIdx.x;
    if (e < E) atomicAdd(&deg[dst[e]], 1);
}

__global__ __launch_bounds__(256) void k_scan_a(const int* __restrict__ deg, int n,
                                                int* __restrict__ bsum) {
    __shared__ int s[256];
    int i = blockIdx.x * 256 + threadIdx.x;
    s[threadIdx.x] = (i < n) ? deg[i] : 0;
    __syncthreads();
    for (int st = 128; st > 0; st >>= 1) {
        if (threadIdx.x < st) s[threadIdx.x] += s[threadIdx.x + st];
        __syncthreads();
    }
    if (threadIdx.x == 0) bsum[blockIdx.x] = s[0];
}

__global__ __launch_bounds__(256) void k_scan_b(int* __restrict__ bsum, int nb) {
    __shared__ int s[256];
    int t = threadIdx.x;
    int v = (t < nb) ? bsum[t] : 0;
    s[t] = v;
    __syncthreads();
    for (int off = 1; off < 256; off <<= 1) {
        int add = (t >= off) ? s[t - off] : 0;
        __syncthreads();
        s[t] += add;
        __syncthreads();
    }
    if (t < nb) bsum[t] = s[t] - v;  // exclusive
}

__global__ __launch_bounds__(256) void k_scan_c(const int* __restrict__ deg, int n,
                                                const int* __restrict__ bsum,
                                                int* __restrict__ rowptr,
                                                int* __restrict__ cursor, int E) {
    __shared__ int s[256];
    int t = threadIdx.x;
    int i = blockIdx.x * 256 + t;
    int v = (i < n) ? deg[i] : 0;
    s[t] = v;
    __syncthreads();
    for (int off = 1; off < 256; off <<= 1) {
        int add = (t >= off) ? s[t - off] : 0;
        __syncthreads();
        s[t] += add;
        __syncthreads();
    }
    if (i < n) {
        int ex = bsum[blockIdx.x] + s[t] - v;
        rowptr[i] = ex;
        cursor[i] = ex;
    }
    if (i == 0) rowptr[n] = E;
}

__global__ __launch_bounds__(256) void k_fill(const int* __restrict__ src,
                                              const int* __restrict__ dst, int E,
                                              int* __restrict__ cursor,
                                              int* __restrict__ csr_src) {
    int e = blockIdx.x * 256 + threadIdx.x;
    if (e < E) {
        int d = dst[e];
        int slot = atomicAdd(&cursor[d], 1);
        csr_src[slot] = src[e];
    }
}

// ---------------- GEMM + fused alpha epilogue -------------------------------
// out[M,256](f16) = A[M,K](f32) @ W[K,256](f32); split==256: single W (row
// stride 256); split==128: cols 0..127 from Wl, 128..255 from Wr (stride 128).
// 256 thr; 64x256 tile, BK=32. Thread: 8 rows (rg=(tid>>5)*8) x 8 cols
// (cg=(tid&31)*4 and cg+128). Epilogue: alpha_src/dst per (row, head-slot)
// from fp32 accs via shfl reduction over the 2^ALOGW lanes owning a slot.
// ALOGW=5: NS=2 slots of 128 ch (layer 1). ALOGW=4: NS=4 slots of 64 (mu|ls).
template <int K, int ALOGW>
__global__ __launch_bounds__(256) void k_gemm(const float* __restrict__ A,
                                              const float* __restrict__ Wl,
                                              const float* __restrict__ Wr, int split,
                                              u16* __restrict__ out,
                                              float* __restrict__ as_out,
                                              float* __restrict__ ad_out,
                                              const float* __restrict__ alo,
                                              const float* __restrict__ ahi,
                                              const float* __restrict__ dlo,
                                              const float* __restrict__ dhi, int M) {
    __shared__ float As[64 * 32];   // 8KB
    __shared__ float Ws[32 * 256];  // 32KB
    const int tid = threadIdx.x;
    const int row0 = blockIdx.x * 64;

    float acc[8][8];
#pragma unroll
    for (int r = 0; r < 8; r++)
#pragma unroll
        for (int c = 0; c < 8; c++) acc[r][c] = 0.f;

    const int cg = (tid & 31) * 4;  // cols cg..cg+3 and cg+128..cg+131
    const int rg = (tid >> 5) * 8;  // rows rg..rg+7

    for (int kc = 0; kc < K; kc += 32) {
        __syncthreads();  // prior chunk's LDS reads done
        // stage A chunk: 64 rows x 32 k = 512 float4, 2 per thread
#pragma unroll
        for (int i = 0; i < 2; i++) {
            int f = tid + i * 256;
            int r = f >> 3, k4 = (f & 7) * 4;
            float4 val = make_float4(0.f, 0.f, 0.f, 0.f);
            if (row0 + r < M)
                val = *(const float4*)(A + (size_t)(row0 + r) * K + kc + k4);
            *(float4*)(&As[r * 32 + k4]) = val;
        }
        // stage W chunk: 32 k x 256 cols = 2048 float4, 8 per thread
#pragma unroll
        for (int i = 0; i < 8; i++) {
            int f = tid + i * 256;
            int k = f >> 6, c = (f & 63) * 4;
            const float* wp;
            if (split == 256)
                wp = Wl + (size_t)(kc + k) * 256 + c;
            else
                wp = (c < 128) ? Wl + (size_t)(kc + k) * 128 + c
                               : Wr + (size_t)(kc + k) * 128 + (c - 128);
            *(float4*)(&Ws[k * 256 + c]) = *(const float4*)wp;
        }
        __syncthreads();
#pragma unroll
        for (int k4 = 0; k4 < 32; k4 += 4) {
            float4 wv[4][2];
#pragma unroll
            for (int j = 0; j < 4; j++) {
                wv[j][0] = *(const float4*)(&Ws[(k4 + j) * 256 + cg]);
                wv[j][1] = *(const float4*)(&Ws[(k4 + j) * 256 + cg + 128]);
            }
#pragma unroll
            for (int r = 0; r < 8; r++) {
                float4 a = *(const float4*)(&As[(rg + r) * 32 + k4]);
                float av[4] = {a.x, a.y, a.z, a.w};
#pragma unroll
                for (int j = 0; j < 4; j++) {
                    acc[r][0] += av[j] * wv[j][0].x;
                    acc[r][1] += av[j] * wv[j][0].y;
                    acc[r][2] += av[j] * wv[j][0].z;
                    acc[r][3] += av[j] * wv[j][0].w;
                    acc[r][4] += av[j] * wv[j][1].x;
                    acc[r][5] += av[j] * wv[j][1].y;
                    acc[r][6] += av[j] * wv[j][1].z;
                    acc[r][7] += av[j] * wv[j][1].w;
                }
            }
        }
    }

    // h store (fp16)
#pragma unroll
    for (int r = 0; r < 8; r++) {
        int row = row0 + rg + r;
        if (row < M) {
            storeh4(out, (size_t)row * 256 + cg,
                    make_float4(acc[r][0], acc[r][1], acc[r][2], acc[r][3]));
            storeh4(out, (size_t)row * 256 + cg + 128,
                    make_float4(acc[r][4], acc[r][5], acc[r][6], acc[r][7]));
        }
    }

    // fused alpha epilogue (fp32 accs -> exact logits)
    {
        const int lane = tid & 63;
        const int NS = 64 >> ALOGW;  // 2 or 4
        const int slot_lo = (ALOGW == 5) ? 0 : ((lane >> 4) & 1);
        float4 asl = *(const float4*)(alo + cg);
        float4 ash = *(const float4*)(ahi + cg);
        float4 adl = *(const float4*)(dlo + cg);
        float4 adh = *(const float4*)(dhi + cg);
#pragma unroll
        for (int r = 0; r < 8; r++) {
            float s0 = acc[r][0] * asl.x + acc[r][1] * asl.y + acc[r][2] * asl.z +
                       acc[r][3] * asl.w;
            float s1 = acc[r][4] * ash.x + acc[r][5] * ash.y + acc[r][6] * ash.z +
                       acc[r][7] * ash.w;
            float d0 = acc[r][0] * adl.x + acc[r][1] * adl.y + acc[r][2] * adl.z +
                       acc[r][3] * adl.w;
            float d1 = acc[r][4] * adh.x + acc[r][5] * adh.y + acc[r][6] * adh.z +
                       acc[r][7] * adh.w;
#pragma unroll
            for (int m = (1 << ALOGW) / 2; m >= 1; m >>= 1) {
                s0 += __shfl_xor(s0, m, 64);
                s1 += __shfl_xor(s1, m, 64);
                d0 += __shfl_xor(d0, m, 64);
                d1 += __shfl_xor(d1, m, 64);
            }
            if ((lane & ((1 << ALOGW) - 1)) == 0) {
                int row = row0 + rg + r;
                if (row < M) {
                    as_out[(size_t)row * NS + slot_lo] = s0;
                    as_out[(size_t)row * NS + slot_lo + NS / 2] = s1;
                    ad_out[(size_t)row * NS + slot_lo] = d0;
                    ad_out[(size_t)row * NS + slot_lo + NS / 2] = d1;
                }
            }
        }
    }
}

// ---------------- aggregation (softmax-weighted gather) ----------------------
// One wave per dst node; lane owns 4 channels (fp16 h); self-loop folded in.
// MODE 0: +bias, ELU, write fp32 x1 [n,256]. MODE 1: +bias, write mu/ls.
template <int LOGW, int MODE>
__global__ __launch_bounds__(256) void k_agg(const u16* __restrict__ h,
                                             const int* __restrict__ rowptr,
                                             const int* __restrict__ csr_src,
                                             const float* __restrict__ as,
                                             const float* __restrict__ ad,
                                             const float* __restrict__ b_lo,
                                             const float* __restrict__ b_hi,
                                             float* __restrict__ outp, int n) {
    const int NS = 64 >> LOGW;
    int wid = blockIdx.x * 4 + (threadIdx.x >> 6);
    int lane = threadIdx.x & 63;
    if (wid >= n) return;
    int slot = lane >> LOGW;
    int c = lane * 4;

    float adv = ad[(size_t)wid * NS + slot];
    float e = as[(size_t)wid * NS + slot] + adv;  // self-loop
    e = fmaxf(e, 0.2f * e);                       // LeakyReLU(0.2)
    float w = __expf(e);
    float denom = w;
    float4 hv = loadh4(h, (size_t)wid * 256 + c);
    float acc0 = w * hv.x, acc1 = w * hv.y, acc2 = w * hv.z, acc3 = w * hv.w;

    int rb = rowptr[wid], re = rowptr[wid + 1];
    for (int p = rb; p < re; ++p) {
        int s = csr_src[p];
        float ev = as[(size_t)s * NS + slot] + adv;
        ev = fmaxf(ev, 0.2f * ev);
        float ww = __expf(ev);
        denom += ww;
        float4 hh = loadh4(h, (size_t)s * 256 + c);
        acc0 += ww * hh.x;
        acc1 += ww * hh.y;
        acc2 += ww * hh.z;
        acc3 += ww * hh.w;
    }
    float inv = 1.0f / (denom + 1e-16f);

    int ci = c & 127;
    const float* bp = (c < 128) ? b_lo : b_hi;
    float4 bv = *(const float4*)(bp + ci);
    float v0 = acc0 * inv + bv.x;
    float v1 = acc1 * inv + bv.y;
    float v2 = acc2 * inv + bv.z;
    float v3 = acc3 * inv + bv.w;

    if (MODE == 0) {  // ELU -> x1 fp32 [n,256]
        v0 = v0 > 0.f ? v0 : expm1f(v0);
        v1 = v1 > 0.f ? v1 : expm1f(v1);
        v2 = v2 > 0.f ? v2 : expm1f(v2);
        v3 = v3 > 0.f ? v3 : expm1f(v3);
        *(float4*)(&outp[(size_t)wid * 256 + c]) = make_float4(v0, v1, v2, v3);
    } else {  // mu (c<128) then logstd, each [n,128] fp32, concatenated
        size_t base = (c < 128) ? ((size_t)wid * 128 + c)
                                : ((size_t)n * 128 + (size_t)wid * 128 + (c - 128));
        *(float4*)(&outp[base]) = make_float4(v0, v1, v2, v3);
    }
}

// ---------------------------------------------------------------------------
extern "C" void kernel_launch(void* const* d_in, const int* in_sizes, int n_in,
                              void* d_out, int out_size, void* d_ws, size_t ws_size,
                              hipStream_t stream) {
    const float* x = (const float*)d_in[0];
    const u32* ebuf = (const u32*)d_in[1];
    const float* W1 = (const float*)d_in[2];
    const float* a_src1 = (const float*)d_in[3];
    const float* a_dst1 = (const float*)d_in[4];
    const float* b1 = (const float*)d_in[5];
    const float* W_mu = (const float*)d_in[6];
    const float* a_src_mu = (const float*)d_in[7];
    const float* a_dst_mu = (const float*)d_in[8];
    const float* b_mu = (const float*)d_in[9];
    const float* W_ls = (const float*)d_in[10];
    const float* a_src_ls = (const float*)d_in[11];
    const float* a_dst_ls = (const float*)d_in[12];
    const float* b_ls = (const float*)d_in[13];

    const int n = in_sizes[0] / 128;  // 50000
    const int E = in_sizes[1] / 2;    // 800000

    char* base = (char*)d_ws;
    size_t off = 0;
    auto alloc = [&](size_t b) -> char* {
        char* p = base + off;
        off = (off + b + 255) & ~(size_t)255;
        return p;
    };
    int* rowptr = (int*)alloc((size_t)(n + 1) * 4);
    int* cursor = (int*)alloc((size_t)n * 4);
    int* csr = (int*)alloc((size_t)E * 4);
    int* bsum = (int*)alloc(256 * 4);
    int* eflag = (int*)alloc(256);
    int* se = (int*)alloc((size_t)E * 4);
    int* de = (int*)alloc((size_t)E * 4);
    float* as = (float*)alloc((size_t)n * 4 * 4);
    float* ad = (float*)alloc((size_t)n * 4 * 4);
    u16* h = (u16*)alloc((size_t)n * 256 * 2);  // fp16 h (both layers)
    float* x1 = (float*)d_out;  // n*256 fp32 scratch; dead before final writes

    const int nb = (n + 255) / 256;
    const int eg = (E + 255) / 256;
    const int ng4 = (n + 3) / 4;
    const int gg = (n + 63) / 64;

    // edge normalize + CSR build (reused by all three convs)
    k_detect<<<1, 256, 0, stream>>>(ebuf, eflag);
    k_extract<<<eg, 256, 0, stream>>>(ebuf, E, eflag, se, de);
    hipMemsetAsync(cursor, 0, (size_t)n * 4, stream);
    k_count<<<eg, 256, 0, stream>>>(de, E, cursor);
    k_scan_a<<<nb, 256, 0, stream>>>(cursor, n, bsum);
    k_scan_b<<<1, 256, 0, stream>>>(bsum, nb);
    k_scan_c<<<nb, 256, 0, stream>>>(cursor, n, bsum, rowptr, cursor, E);
    k_fill<<<eg, 256, 0, stream>>>(se, de, E, cursor, csr);

    // Layer 1: h = x@W1 (fp16) + fused alphas; aggregate -> ELU -> x1 (fp32)
    k_gemm<128, 5><<<gg, 256, 0, stream>>>(x, W1, W1, 256, h, as, ad, a_src1,
                                           a_src1 + 128, a_dst1, a_dst1 + 128, n);
    k_agg<5, 0><<<ng4, 256, 0, stream>>>(h, rowptr, csr, as, ad, b1, b1 + 128, x1,
                                         n);

    // Layers mu & ls fused: h = x1@[W_mu|W_ls] (fp16) + fused alphas; aggregate
    k_gemm<256, 4><<<gg, 256, 0, stream>>>(x1, W_mu, W_ls, 128, h, as, ad, a_src_mu,
                                           a_src_ls, a_dst_mu, a_dst_ls, n);
    k_agg<4, 1><<<ng4, 256, 0, stream>>>(h, rowptr, csr, as, ad, b_mu, b_ls,
                                         (float*)d_out, n);
}

// Round 6
// 438.417 us; speedup vs baseline: 1.4693x; 1.3727x over previous
//
#include <hip/hip_runtime.h>

// ---------------------------------------------------------------------------
// GAT encoder: x --GATConv(2 heads,128)--> ELU --> {GATConv mu, GATConv ls}
// N=50000, E=800000 (+self loops). fp32 in/out. Edges int32 w/ int64 detect.
// Round 6:
//  * GEMMs -> MFMA f16 (mfma_f32_16x16x32_f16, HW-verified layouts). LDS-free:
//    W pre-transposed to fp16 Wt[256][K]; x/x1 kept fp16; per-wave direct
//    global fragment loads (one 64B line per lane-load).  Was: fp32 VALU GEMM
//    at 159us/dispatch, VALUBusy 32%.
//  * k_agg edge loop unrolled x4 (4 gathers in flight) - was latency-bound
//    (VALUBusy 19%, 124us).
//  * alphas from fp16 h in a separate tiny kernel (round-4 structure).
// ---------------------------------------------------------------------------

typedef unsigned short u16;
typedef unsigned int u32;
typedef _Float16 f16;
typedef f16 f16x8 __attribute__((ext_vector_type(8)));
typedef float f32x4v __attribute__((ext_vector_type(4)));

__device__ __forceinline__ u16 f2h(float f) {
    union { f16 h; u16 u; } t;
    t.h = (f16)f;
    return t.u;
}
__device__ __forceinline__ float4 loadh4(const u16* __restrict__ p, size_t i) {
    union { uint2 u; f16 h[4]; } t;
    t.u = *(const uint2*)(p + i);
    return make_float4((float)t.h[0], (float)t.h[1], (float)t.h[2], (float)t.h[3]);
}
__device__ __forceinline__ void store4(float* __restrict__ p, size_t i, float4 v) {
    *(float4*)(p + i) = v;
}
__device__ __forceinline__ void store4(u16* __restrict__ p, size_t i, float4 v) {
    union { uint2 u; f16 h[4]; } t;
    t.h[0] = (f16)v.x; t.h[1] = (f16)v.y; t.h[2] = (f16)v.z; t.h[3] = (f16)v.w;
    *(uint2*)(p + i) = t.u;
}

// ---------------- edge dtype detect + normalize (+degree count) --------------
__global__ __launch_bounds__(256) void k_detect(const u32* __restrict__ ebuf,
                                                int* __restrict__ flag) {
    __shared__ int nz;
    if (threadIdx.x == 0) nz = 0;
    __syncthreads();
    if (ebuf[2 * threadIdx.x + 1] != 0u) atomicAdd(&nz, 1);
    __syncthreads();
    if (threadIdx.x == 0) *flag = (nz == 0) ? 1 : 0;
}

__global__ __launch_bounds__(256) void k_extract(const u32* __restrict__ ebuf, int E,
                                                 const int* __restrict__ flag,
                                                 int* __restrict__ se,
                                                 int* __restrict__ de,
                                                 int* __restrict__ deg) {
    int e = blockIdx.x * 256 + threadIdx.x;
    if (e >= E) return;
    int s, d;
    if (*flag) {  // int64 layout
        s = (int)ebuf[2 * (size_t)e];
        d = (int)ebuf[2 * ((size_t)E + (size_t)e)];
    } else {  // int32 layout
        s = (int)ebuf[e];
        d = (int)ebuf[(size_t)E + (size_t)e];
    }
    se[e] = s;
    de[e] = d;
    atomicAdd(&deg[d], 1);
}

// ---------------- CSR build ----------------
__global__ __launch_bounds__(256) void k_scan_a(const int* __restrict__ deg, int n,
                                                int* __restrict__ bsum) {
    __shared__ int s[256];
    int i = blockIdx.x * 256 + threadIdx.x;
    s[threadIdx.x] = (i < n) ? deg[i] : 0;
    __syncthreads();
    for (int st = 128; st > 0; st >>= 1) {
        if (threadIdx.x < st) s[threadIdx.x] += s[threadIdx.x + st];
        __syncthreads();
    }
    if (threadIdx.x == 0) bsum[blockIdx.x] = s[0];
}

__global__ __launch_bounds__(256) void k_scan_b(int* __restrict__ bsum, int nb) {
    __shared__ int s[256];
    int t = threadIdx.x;
    int v = (t < nb) ? bsum[t] : 0;
    s[t] = v;
    __syncthreads();
    for (int off = 1; off < 256; off <<= 1) {
        int add = (t >= off) ? s[t - off] : 0;
        __syncthreads();
        s[t] += add;
        __syncthreads();
    }
    if (t < nb) bsum[t] = s[t] - v;  // exclusive
}

__global__ __launch_bounds__(256) void k_scan_c(const int* __restrict__ deg, int n,
                                                const int* __restrict__ bsum,
                                                int* __restrict__ rowptr,
                                                int* __restrict__ cursor, int E) {
    __shared__ int s[256];
    int t = threadIdx.x;
    int i = blockIdx.x * 256 + t;
    int v = (i < n) ? deg[i] : 0;
    s[t] = v;
    __syncthreads();
    for (int off = 1; off < 256; off <<= 1) {
        int add = (t >= off) ? s[t - off] : 0;
        __syncthreads();
        s[t] += add;
        __syncthreads();
    }
    if (i < n) {
        int ex = bsum[blockIdx.x] + s[t] - v;
        rowptr[i] = ex;
        cursor[i] = ex;
    }
    if (i == 0) rowptr[n] = E;
}

__global__ __launch_bounds__(256) void k_fill(const int* __restrict__ src,
                                              const int* __restrict__ dst, int E,
                                              int* __restrict__ cursor,
                                              int* __restrict__ csr_src) {
    int e = blockIdx.x * 256 + threadIdx.x;
    if (e < E) {
        int d = dst[e];
        int slot = atomicAdd(&cursor[d], 1);
        csr_src[slot] = src[e];
    }
}

// ---------------- fp32 -> fp16 conversions ----------------------------------
__global__ __launch_bounds__(256) void k_cvt(const float* __restrict__ in,
                                             u16* __restrict__ out, int nElem) {
    int i = (blockIdx.x * 256 + threadIdx.x) * 4;
    if (i >= nElem) return;
    float4 v = *(const float4*)(in + i);
    store4(out, i, v);
}

// Wt[c][k] = W[k][c] as fp16.  split==256: single W (row stride 256);
// split==128: c<128 from Wl, else Wr (row stride 128).
__global__ __launch_bounds__(256) void k_tw(const float* __restrict__ Wl,
                                            const float* __restrict__ Wr, int split,
                                            int K, u16* __restrict__ Wt) {
    int idx = blockIdx.x * 256 + threadIdx.x;
    if (idx >= 256 * K) return;
    int c = idx / K, k = idx - c * K;
    float v;
    if (split == 256)
        v = Wl[(size_t)k * 256 + c];
    else
        v = (c < 128) ? Wl[(size_t)k * 128 + c] : Wr[(size_t)k * 128 + (c - 128)];
    Wt[idx] = f2h(v);
}

// ---------------- MFMA GEMM: h[M,256](f16) = A[M,K](f16) @ W[K,256] ---------
// Wt is W transposed: Wt[c][k], fp16, rows 16B-aligned. One wave (64 thr) per
// 16-row strip; 16 col-tiles of 16; K in chunks of 32 via mfma_f32_16x16x32_f16.
// Verified layouts: A[m=lane&15][k=(lane>>4)*8+j]; B mirrors with n=lane&15;
// D: col=lane&15, row=(lane>>4)*4+reg.
template <int K>
__global__ __launch_bounds__(64) void k_gemm_mfma(const u16* __restrict__ Ah,
                                                  const u16* __restrict__ Wt,
                                                  u16* __restrict__ out, int M) {
    const int lane = threadIdx.x;
    const int r0 = blockIdx.x * 16;
    const int li = lane & 15;
    const int quad = lane >> 4;  // 0..3
    int row = r0 + li;
    if (row >= M) row = M - 1;
    const u16* arow = Ah + (size_t)row * K + quad * 8;

    f32x4v acc[16];
#pragma unroll
    for (int ct = 0; ct < 16; ct++) acc[ct] = (f32x4v)(0.f);

    for (int t = 0; t < K; t += 32) {
        f16x8 a = *(const f16x8*)(arow + t);
#pragma unroll
        for (int ct = 0; ct < 16; ct++) {
            const u16* brow = Wt + (size_t)(ct * 16 + li) * K + t + quad * 8;
            f16x8 b = *(const f16x8*)brow;
            acc[ct] = __builtin_amdgcn_mfma_f32_16x16x32_f16(a, b, acc[ct], 0, 0, 0);
        }
    }

#pragma unroll
    for (int reg = 0; reg < 4; reg++) {
        int grow = r0 + quad * 4 + reg;
        if (grow < M) {
            u16* orow = out + (size_t)grow * 256 + li;
#pragma unroll
            for (int ct = 0; ct < 16; ct++) orow[ct * 16] = f2h(acc[ct][reg]);
        }
    }
}

// ---------------- attention logits: as/ad[n,NS] ------------------------------
// One wave per node; lane l owns channels 4l..4l+3 of h[n,256] (fp16).
// LOGW=5: 2 slots of 128 ch (layer 1). LOGW=4: 4 slots of 64 ch (mu|ls).
template <int LOGW>
__global__ __launch_bounds__(256) void k_alphas(const u16* __restrict__ h,
                                                const float* __restrict__ as_lo,
                                                const float* __restrict__ as_hi,
                                                const float* __restrict__ ad_lo,
                                                const float* __restrict__ ad_hi,
                                                float* __restrict__ as_out,
                                                float* __restrict__ ad_out, int n) {
    const int W = 1 << LOGW;
    const int NS = 64 >> LOGW;
    int wid = blockIdx.x * 4 + (threadIdx.x >> 6);
    int lane = threadIdx.x & 63;
    if (wid >= n) return;
    int c = lane * 4;
    int ci = c & 127;
    const float* ap = (c < 128) ? as_lo : as_hi;
    const float* dp = (c < 128) ? ad_lo : ad_hi;
    float4 hv = loadh4(h, (size_t)wid * 256 + c);
    float4 av = *(const float4*)(ap + ci);
    float4 dv = *(const float4*)(dp + ci);
    float ssum = hv.x * av.x + hv.y * av.y + hv.z * av.z + hv.w * av.w;
    float dsum = hv.x * dv.x + hv.y * dv.y + hv.z * dv.z + hv.w * dv.w;
#pragma unroll
    for (int m = W / 2; m >= 1; m >>= 1) {
        ssum += __shfl_xor(ssum, m, 64);
        dsum += __shfl_xor(dsum, m, 64);
    }
    if ((lane & (W - 1)) == 0) {
        int slot = lane >> LOGW;
        as_out[(size_t)wid * NS + slot] = ssum;
        ad_out[(size_t)wid * NS + slot] = dsum;
    }
}

// ---------------- aggregation (softmax-weighted gather, 4-wide MLP) ----------
// One wave per dst node; lane owns 4 channels (fp16 h); self-loop folded in.
// Edge loop unrolled x4: 4 independent as-loads + h-gathers in flight.
// MODE 0: +bias, ELU, write fp16 x1 [n,256]. MODE 1: +bias, write fp32 mu/ls.
template <int LOGW, int MODE, typename OT>
__global__ __launch_bounds__(256) void k_agg(const u16* __restrict__ h,
                                             const int* __restrict__ rowptr,
                                             const int* __restrict__ csr_src,
                                             const float* __restrict__ as,
                                             const float* __restrict__ ad,
                                             const float* __restrict__ b_lo,
                                             const float* __restrict__ b_hi,
                                             OT* __restrict__ outp, int n) {
    const int NS = 64 >> LOGW;
    int wid = blockIdx.x * 4 + (threadIdx.x >> 6);
    int lane = threadIdx.x & 63;
    if (wid >= n) return;
    int slot = lane >> LOGW;
    int c = lane * 4;

    float adv = ad[(size_t)wid * NS + slot];
    float e = as[(size_t)wid * NS + slot] + adv;  // self-loop
    e = fmaxf(e, 0.2f * e);                       // LeakyReLU(0.2)
    float w = __expf(e);
    float denom = w;
    float4 hv = loadh4(h, (size_t)wid * 256 + c);
    float acc0 = w * hv.x, acc1 = w * hv.y, acc2 = w * hv.z, acc3 = w * hv.w;

    const int rb = rowptr[wid], re = rowptr[wid + 1];
    int p = rb;
    for (; p + 4 <= re; p += 4) {
        int s0 = csr_src[p], s1 = csr_src[p + 1];
        int s2 = csr_src[p + 2], s3 = csr_src[p + 3];
        float e0 = as[(size_t)s0 * NS + slot] + adv;
        float e1 = as[(size_t)s1 * NS + slot] + adv;
        float e2 = as[(size_t)s2 * NS + slot] + adv;
        float e3 = as[(size_t)s3 * NS + slot] + adv;
        e0 = fmaxf(e0, 0.2f * e0);
        e1 = fmaxf(e1, 0.2f * e1);
        e2 = fmaxf(e2, 0.2f * e2);
        e3 = fmaxf(e3, 0.2f * e3);
        float w0 = __expf(e0), w1 = __expf(e1), w2 = __expf(e2), w3 = __expf(e3);
        float4 h0 = loadh4(h, (size_t)s0 * 256 + c);
        float4 h1 = loadh4(h, (size_t)s1 * 256 + c);
        float4 h2 = loadh4(h, (size_t)s2 * 256 + c);
        float4 h3 = loadh4(h, (size_t)s3 * 256 + c);
        denom += (w0 + w1) + (w2 + w3);
        acc0 += w0 * h0.x + w1 * h1.x + w2 * h2.x + w3 * h3.x;
        acc1 += w0 * h0.y + w1 * h1.y + w2 * h2.y + w3 * h3.y;
        acc2 += w0 * h0.z + w1 * h1.z + w2 * h2.z + w3 * h3.z;
        acc3 += w0 * h0.w + w1 * h1.w + w2 * h2.w + w3 * h3.w;
    }
    for (; p < re; ++p) {
        int s = csr_src[p];
        float ev = as[(size_t)s * NS + slot] + adv;
        ev = fmaxf(ev, 0.2f * ev);
        float ww = __expf(ev);
        denom += ww;
        float4 hh = loadh4(h, (size_t)s * 256 + c);
        acc0 += ww * hh.x;
        acc1 += ww * hh.y;
        acc2 += ww * hh.z;
        acc3 += ww * hh.w;
    }
    float inv = 1.0f / (denom + 1e-16f);

    int ci = c & 127;
    const float* bp = (c < 128) ? b_lo : b_hi;
    float4 bv = *(const float4*)(bp + ci);
    float v0 = acc0 * inv + bv.x;
    float v1 = acc1 * inv + bv.y;
    float v2 = acc2 * inv + bv.z;
    float v3 = acc3 * inv + bv.w;

    if (MODE == 0) {  // ELU -> x1 fp16 [n,256]
        v0 = v0 > 0.f ? v0 : expm1f(v0);
        v1 = v1 > 0.f ? v1 : expm1f(v1);
        v2 = v2 > 0.f ? v2 : expm1f(v2);
        v3 = v3 > 0.f ? v3 : expm1f(v3);
        store4(outp, (size_t)wid * 256 + c, make_float4(v0, v1, v2, v3));
    } else {  // mu (c<128) then logstd, each [n,128] fp32, concatenated
        size_t base = (c < 128) ? ((size_t)wid * 128 + c)
                                : ((size_t)n * 128 + (size_t)wid * 128 + (c - 128));
        store4(outp, base, make_float4(v0, v1, v2, v3));
    }
}

// ---------------------------------------------------------------------------
extern "C" void kernel_launch(void* const* d_in, const int* in_sizes, int n_in,
                              void* d_out, int out_size, void* d_ws, size_t ws_size,
                              hipStream_t stream) {
    const float* x = (const float*)d_in[0];
    const u32* ebuf = (const u32*)d_in[1];
    const float* W1 = (const float*)d_in[2];
    const float* a_src1 = (const float*)d_in[3];
    const float* a_dst1 = (const float*)d_in[4];
    const float* b1 = (const float*)d_in[5];
    const float* W_mu = (const float*)d_in[6];
    const float* a_src_mu = (const float*)d_in[7];
    const float* a_dst_mu = (const float*)d_in[8];
    const float* b_mu = (const float*)d_in[9];
    const float* W_ls = (const float*)d_in[10];
    const float* a_src_ls = (const float*)d_in[11];
    const float* a_dst_ls = (const float*)d_in[12];
    const float* b_ls = (const float*)d_in[13];

    const int n = in_sizes[0] / 128;  // 50000
    const int E = in_sizes[1] / 2;    // 800000

    char* base = (char*)d_ws;
    size_t off = 0;
    auto alloc = [&](size_t b) -> char* {
        char* p = base + off;
        off = (off + b + 255) & ~(size_t)255;
        return p;
    };
    int* rowptr = (int*)alloc((size_t)(n + 1) * 4);
    int* cursor = (int*)alloc((size_t)n * 4);
    int* csr = (int*)alloc((size_t)E * 4);
    int* bsum = (int*)alloc(256 * 4);
    int* eflag = (int*)alloc(256);
    int* se = (int*)alloc((size_t)E * 4);
    int* de = (int*)alloc((size_t)E * 4);
    float* as = (float*)alloc((size_t)n * 4 * 4);
    float* ad = (float*)alloc((size_t)n * 4 * 4);
    u16* W1t = (u16*)alloc(256 * 128 * 2);        // W1^T fp16 [256][128]
    u16* Wt2 = (u16*)alloc(256 * 256 * 2);        // [W_mu|W_ls]^T fp16 [256][256]
    u16* x1h = (u16*)alloc((size_t)n * 256 * 2);  // x1 fp16 [n,256]
    u16* xh = x1h;  // alias: xh fp16 [n,128] dead before x1h written
    u16* h = (u16*)alloc((size_t)n * 256 * 2);    // h fp16 (both layers)

    const int nb = (n + 255) / 256;
    const int eg = (E + 255) / 256;
    const int ng4 = (n + 3) / 4;
    const int gm = (n + 15) / 16;

    // edge normalize + CSR build (reused by all three convs)
    hipMemsetAsync(cursor, 0, (size_t)n * 4, stream);
    k_detect<<<1, 256, 0, stream>>>(ebuf, eflag);
    k_extract<<<eg, 256, 0, stream>>>(ebuf, E, eflag, se, de, cursor);
    k_scan_a<<<nb, 256, 0, stream>>>(cursor, n, bsum);
    k_scan_b<<<1, 256, 0, stream>>>(bsum, nb);
    k_scan_c<<<nb, 256, 0, stream>>>(cursor, n, bsum, rowptr, cursor, E);
    k_fill<<<eg, 256, 0, stream>>>(se, de, E, cursor, csr);

    // fp16 conversions / weight transposes
    k_cvt<<<(n * 128 / 4 + 255) / 256, 256, 0, stream>>>(x, xh, n * 128);
    k_tw<<<(256 * 128 + 255) / 256, 256, 0, stream>>>(W1, W1, 256, 128, W1t);
    k_tw<<<(256 * 256 + 255) / 256, 256, 0, stream>>>(W_mu, W_ls, 128, 256, Wt2);

    // Layer 1: h = x@W1 (MFMA); alphas; aggregate -> ELU -> x1 (fp16)
    k_gemm_mfma<128><<<gm, 64, 0, stream>>>(xh, W1t, h, n);
    k_alphas<5><<<ng4, 256, 0, stream>>>(h, a_src1, a_src1 + 128, a_dst1,
                                         a_dst1 + 128, as, ad, n);
    k_agg<5, 0, u16><<<ng4, 256, 0, stream>>>(h, rowptr, csr, as, ad, b1, b1 + 128,
                                              x1h, n);

    // Layers mu & ls fused: h = x1@[W_mu|W_ls] (MFMA); alphas; aggregate
    k_gemm_mfma<256><<<gm, 64, 0, stream>>>(x1h, Wt2, h, n);
    k_alphas<4><<<ng4, 256, 0, stream>>>(h, a_src_mu, a_src_ls, a_dst_mu, a_dst_ls,
                                         as, ad, n);
    k_agg<4, 1, float><<<ng4, 256, 0, stream>>>(h, rowptr, csr, as, ad, b_mu, b_ls,
                                                (float*)d_out, n);
}

// Round 7
// 383.995 us; speedup vs baseline: 1.6775x; 1.1417x over previous
//
#include <hip/hip_runtime.h>

// ---------------------------------------------------------------------------
// GAT encoder: x --GATConv(2 heads,128)--> ELU --> {GATConv mu, GATConv ls}
// N=50000, E=800000 (+self loops). fp32 in/out. Edges int32 w/ int64 detect.
// Round 7:
//  * MFMA GEMM now stages Wt chunks in LDS (20KB, pad-40 rows): 4 waves/block
//    share each 256x32 B-chunk; B traffic 400MB L2 -> 100MB global + LDS.
//    (was: every wave re-read all of Wt from L2, latency-bound K-loop)
//  * alphas fused into GEMM epilogue from fp32 accs (removes 2 kernels + 2x
//    25.6MB h re-reads; logits computed pre-fp16-quantization).
//  * k_agg unchanged (68us, FETCH 210MB = 8.2x XCD amplification, structural).
// ---------------------------------------------------------------------------

typedef unsigned short u16;
typedef unsigned int u32;
typedef _Float16 f16;
typedef f16 f16x8 __attribute__((ext_vector_type(8)));
typedef float f32x4v __attribute__((ext_vector_type(4)));

__device__ __forceinline__ u16 f2h(float f) {
    union { f16 h; u16 u; } t;
    t.h = (f16)f;
    return t.u;
}
__device__ __forceinline__ float4 loadh4(const u16* __restrict__ p, size_t i) {
    union { uint2 u; f16 h[4]; } t;
    t.u = *(const uint2*)(p + i);
    return make_float4((float)t.h[0], (float)t.h[1], (float)t.h[2], (float)t.h[3]);
}
__device__ __forceinline__ void store4(float* __restrict__ p, size_t i, float4 v) {
    *(float4*)(p + i) = v;
}
__device__ __forceinline__ void store4(u16* __restrict__ p, size_t i, float4 v) {
    union { uint2 u; f16 h[4]; } t;
    t.h[0] = (f16)v.x; t.h[1] = (f16)v.y; t.h[2] = (f16)v.z; t.h[3] = (f16)v.w;
    *(uint2*)(p + i) = t.u;
}

// ---------------- edge dtype detect + normalize (+degree count) --------------
__global__ __launch_bounds__(256) void k_detect(const u32* __restrict__ ebuf,
                                                int* __restrict__ flag) {
    __shared__ int nz;
    if (threadIdx.x == 0) nz = 0;
    __syncthreads();
    if (ebuf[2 * threadIdx.x + 1] != 0u) atomicAdd(&nz, 1);
    __syncthreads();
    if (threadIdx.x == 0) *flag = (nz == 0) ? 1 : 0;
}

__global__ __launch_bounds__(256) void k_extract(const u32* __restrict__ ebuf, int E,
                                                 const int* __restrict__ flag,
                                                 int* __restrict__ se,
                                                 int* __restrict__ de,
                                                 int* __restrict__ deg) {
    int e = blockIdx.x * 256 + threadIdx.x;
    if (e >= E) return;
    int s, d;
    if (*flag) {  // int64 layout
        s = (int)ebuf[2 * (size_t)e];
        d = (int)ebuf[2 * ((size_t)E + (size_t)e)];
    } else {  // int32 layout
        s = (int)ebuf[e];
        d = (int)ebuf[(size_t)E + (size_t)e];
    }
    se[e] = s;
    de[e] = d;
    atomicAdd(&deg[d], 1);
}

// ---------------- CSR build ----------------
__global__ __launch_bounds__(256) void k_scan_a(const int* __restrict__ deg, int n,
                                                int* __restrict__ bsum) {
    __shared__ int s[256];
    int i = blockIdx.x * 256 + threadIdx.x;
    s[threadIdx.x] = (i < n) ? deg[i] : 0;
    __syncthreads();
    for (int st = 128; st > 0; st >>= 1) {
        if (threadIdx.x < st) s[threadIdx.x] += s[threadIdx.x + st];
        __syncthreads();
    }
    if (threadIdx.x == 0) bsum[blockIdx.x] = s[0];
}

__global__ __launch_bounds__(256) void k_scan_b(int* __restrict__ bsum, int nb) {
    __shared__ int s[256];
    int t = threadIdx.x;
    int v = (t < nb) ? bsum[t] : 0;
    s[t] = v;
    __syncthreads();
    for (int off = 1; off < 256; off <<= 1) {
        int add = (t >= off) ? s[t - off] : 0;
        __syncthreads();
        s[t] += add;
        __syncthreads();
    }
    if (t < nb) bsum[t] = s[t] - v;  // exclusive
}

__global__ __launch_bounds__(256) void k_scan_c(const int* __restrict__ deg, int n,
                                                const int* __restrict__ bsum,
                                                int* __restrict__ rowptr,
                                                int* __restrict__ cursor, int E) {
    __shared__ int s[256];
    int t = threadIdx.x;
    int i = blockIdx.x * 256 + t;
    int v = (i < n) ? deg[i] : 0;
    s[t] = v;
    __syncthreads();
    for (int off = 1; off < 256; off <<= 1) {
        int add = (t >= off) ? s[t - off] : 0;
        __syncthreads();
        s[t] += add;
        __syncthreads();
    }
    if (i < n) {
        int ex = bsum[blockIdx.x] + s[t] - v;
        rowptr[i] = ex;
        cursor[i] = ex;
    }
    if (i == 0) rowptr[n] = E;
}

__global__ __launch_bounds__(256) void k_fill(const int* __restrict__ src,
                                              const int* __restrict__ dst, int E,
                                              int* __restrict__ cursor,
                                              int* __restrict__ csr_src) {
    int e = blockIdx.x * 256 + threadIdx.x;
    if (e < E) {
        int d = dst[e];
        int slot = atomicAdd(&cursor[d], 1);
        csr_src[slot] = src[e];
    }
}

// ---------------- fp32 -> fp16 conversions ----------------------------------
__global__ __launch_bounds__(256) void k_cvt(const float* __restrict__ in,
                                             u16* __restrict__ out, int nElem) {
    int i = (blockIdx.x * 256 + threadIdx.x) * 4;
    if (i >= nElem) return;
    float4 v = *(const float4*)(in + i);
    store4(out, i, v);
}

// Wt[c][k] = W[k][c] as fp16.  split==256: single W (row stride 256);
// split==128: c<128 from Wl, else Wr (row stride 128).
__global__ __launch_bounds__(256) void k_tw(const float* __restrict__ Wl,
                                            const float* __restrict__ Wr, int split,
                                            int K, u16* __restrict__ Wt) {
    int idx = blockIdx.x * 256 + threadIdx.x;
    if (idx >= 256 * K) return;
    int c = idx / K, k = idx - c * K;
    float v;
    if (split == 256)
        v = Wl[(size_t)k * 256 + c];
    else
        v = (c < 128) ? Wl[(size_t)k * 128 + c] : Wr[(size_t)k * 128 + (c - 128)];
    Wt[idx] = f2h(v);
}

// ---------------- MFMA GEMM + fused alpha epilogue --------------------------
// h[M,256](f16) = A[M,K](f16) @ W[K,256]; Wt = W^T fp16 [256][K].
// Block: 256 thr = 4 waves; wave w owns rows r0=blk*64+w*16; per K-chunk of 32
// all waves share Bs (256 cols x 32 k, rows padded to 40 halfwords: 16B-
// aligned ds_read_b128, <=2-way banks). mfma_f32_16x16x32_f16 layouts (HW-
// verified): A[m=lane&15][k=quad*8+j]; B[n=lane&15][k]; D col=lane&15,
// row=quad*4+reg. Epilogue computes as/ad[row,slot] from fp32 accs:
// ALOGW=5 -> 2 slots of 128 cols; ALOGW=4 -> 4 slots of 64 cols.
template <int K, int ALOGW>
__global__ __launch_bounds__(256) void k_gemm_mfma(
    const u16* __restrict__ Ah, const u16* __restrict__ Wt, u16* __restrict__ out,
    float* __restrict__ as_out, float* __restrict__ ad_out,
    const float* __restrict__ alo, const float* __restrict__ ahi,
    const float* __restrict__ dlo, const float* __restrict__ dhi, int M) {
    __shared__ u16 Bs[256 * 40];  // 20KB
    const int tid = threadIdx.x;
    const int wave = tid >> 6;
    const int lane = tid & 63;
    const int li = lane & 15;
    const int quad = lane >> 4;
    const int r0 = blockIdx.x * 64 + wave * 16;
    int arowi = r0 + li;
    if (arowi >= M) arowi = M - 1;  // clamp (stores are guarded)
    const u16* arow = Ah + (size_t)arowi * K + quad * 8;

    f32x4v acc[16];
#pragma unroll
    for (int ct = 0; ct < 16; ct++) acc[ct] = (f32x4v)(0.f);

    for (int t = 0; t < K; t += 32) {
        __syncthreads();  // prior chunk's ds_reads done
        // stage Wt[:, t..t+31]: thread tid stages row c=tid (64B = 4x uint4)
        {
            const u16* src = Wt + (size_t)tid * K + t;
            u16* dst = Bs + tid * 40;
            uint4 v0 = ((const uint4*)src)[0];
            uint4 v1 = ((const uint4*)src)[1];
            uint4 v2 = ((const uint4*)src)[2];
            uint4 v3 = ((const uint4*)src)[3];
            ((uint4*)dst)[0] = v0;
            ((uint4*)(dst + 8))[0] = v1;
            ((uint4*)(dst + 16))[0] = v2;
            ((uint4*)(dst + 24))[0] = v3;
        }
        __syncthreads();
        f16x8 a = *(const f16x8*)(arow + t);
#pragma unroll
        for (int ct = 0; ct < 16; ct++) {
            f16x8 b = *(const f16x8*)(Bs + (ct * 16 + li) * 40 + quad * 8);
            acc[ct] = __builtin_amdgcn_mfma_f32_16x16x32_f16(a, b, acc[ct], 0, 0, 0);
        }
    }

    // h store (fp16): D row = quad*4+reg, col = ct*16+li
#pragma unroll
    for (int reg = 0; reg < 4; reg++) {
        int grow = r0 + quad * 4 + reg;
        if (grow < M) {
            u16* orow = out + (size_t)grow * 256 + li;
#pragma unroll
            for (int ct = 0; ct < 16; ct++) orow[ct * 16] = f2h(acc[ct][reg]);
        }
    }

    // fused alpha epilogue
    const int NS = 64 >> ALOGW;   // 2 or 4
    const int SH = ALOGW - 2;     // slot = ct >> SH
    float aw[16], dw[16];
#pragma unroll
    for (int ct = 0; ct < 16; ct++) {
        int col = ct * 16 + li;
        aw[ct] = (col < 128) ? alo[col] : ahi[col - 128];
        dw[ct] = (col < 128) ? dlo[col] : dhi[col - 128];
    }
#pragma unroll
    for (int reg = 0; reg < 4; reg++) {
        float s[4] = {0.f, 0.f, 0.f, 0.f};
        float d[4] = {0.f, 0.f, 0.f, 0.f};
#pragma unroll
        for (int ct = 0; ct < 16; ct++) {
            int sl = ct >> SH;
            s[sl] += acc[ct][reg] * aw[ct];
            d[sl] += acc[ct][reg] * dw[ct];
        }
#pragma unroll
        for (int sl = 0; sl < NS; sl++) {
#pragma unroll
            for (int m = 1; m <= 8; m <<= 1) {
                s[sl] += __shfl_xor(s[sl], m, 64);
                d[sl] += __shfl_xor(d[sl], m, 64);
            }
        }
        int grow = r0 + quad * 4 + reg;
        if (li == 0 && grow < M) {
#pragma unroll
            for (int sl = 0; sl < NS; sl++) {
                as_out[(size_t)grow * NS + sl] = s[sl];
                ad_out[(size_t)grow * NS + sl] = d[sl];
            }
        }
    }
}

// ---------------- aggregation (softmax-weighted gather, 4-wide MLP) ----------
// One wave per dst node; lane owns 4 channels (fp16 h); self-loop folded in.
// MODE 0: +bias, ELU, write fp16 x1 [n,256]. MODE 1: +bias, write fp32 mu/ls.
template <int LOGW, int MODE, typename OT>
__global__ __launch_bounds__(256) void k_agg(const u16* __restrict__ h,
                                             const int* __restrict__ rowptr,
                                             const int* __restrict__ csr_src,
                                             const float* __restrict__ as,
                                             const float* __restrict__ ad,
                                             const float* __restrict__ b_lo,
                                             const float* __restrict__ b_hi,
                                             OT* __restrict__ outp, int n) {
    const int NS = 64 >> LOGW;
    int wid = blockIdx.x * 4 + (threadIdx.x >> 6);
    int lane = threadIdx.x & 63;
    if (wid >= n) return;
    int slot = lane >> LOGW;
    int c = lane * 4;

    float adv = ad[(size_t)wid * NS + slot];
    float e = as[(size_t)wid * NS + slot] + adv;  // self-loop
    e = fmaxf(e, 0.2f * e);                       // LeakyReLU(0.2)
    float w = __expf(e);
    float denom = w;
    float4 hv = loadh4(h, (size_t)wid * 256 + c);
    float acc0 = w * hv.x, acc1 = w * hv.y, acc2 = w * hv.z, acc3 = w * hv.w;

    const int rb = rowptr[wid], re = rowptr[wid + 1];
    int p = rb;
    for (; p + 4 <= re; p += 4) {
        int s0 = csr_src[p], s1 = csr_src[p + 1];
        int s2 = csr_src[p + 2], s3 = csr_src[p + 3];
        float e0 = as[(size_t)s0 * NS + slot] + adv;
        float e1 = as[(size_t)s1 * NS + slot] + adv;
        float e2 = as[(size_t)s2 * NS + slot] + adv;
        float e3 = as[(size_t)s3 * NS + slot] + adv;
        e0 = fmaxf(e0, 0.2f * e0);
        e1 = fmaxf(e1, 0.2f * e1);
        e2 = fmaxf(e2, 0.2f * e2);
        e3 = fmaxf(e3, 0.2f * e3);
        float w0 = __expf(e0), w1 = __expf(e1), w2 = __expf(e2), w3 = __expf(e3);
        float4 h0 = loadh4(h, (size_t)s0 * 256 + c);
        float4 h1 = loadh4(h, (size_t)s1 * 256 + c);
        float4 h2 = loadh4(h, (size_t)s2 * 256 + c);
        float4 h3 = loadh4(h, (size_t)s3 * 256 + c);
        denom += (w0 + w1) + (w2 + w3);
        acc0 += w0 * h0.x + w1 * h1.x + w2 * h2.x + w3 * h3.x;
        acc1 += w0 * h0.y + w1 * h1.y + w2 * h2.y + w3 * h3.y;
        acc2 += w0 * h0.z + w1 * h1.z + w2 * h2.z + w3 * h3.z;
        acc3 += w0 * h0.w + w1 * h1.w + w2 * h2.w + w3 * h3.w;
    }
    for (; p < re; ++p) {
        int s = csr_src[p];
        float ev = as[(size_t)s * NS + slot] + adv;
        ev = fmaxf(ev, 0.2f * ev);
        float ww = __expf(ev);
        denom += ww;
        float4 hh = loadh4(h, (size_t)s * 256 + c);
        acc0 += ww * hh.x;
        acc1 += ww * hh.y;
        acc2 += ww * hh.z;
        acc3 += ww * hh.w;
    }
    float inv = 1.0f / (denom + 1e-16f);

    int ci = c & 127;
    const float* bp = (c < 128) ? b_lo : b_hi;
    float4 bv = *(const float4*)(bp + ci);
    float v0 = acc0 * inv + bv.x;
    float v1 = acc1 * inv + bv.y;
    float v2 = acc2 * inv + bv.z;
    float v3 = acc3 * inv + bv.w;

    if (MODE == 0) {  // ELU -> x1 fp16 [n,256]
        v0 = v0 > 0.f ? v0 : expm1f(v0);
        v1 = v1 > 0.f ? v1 : expm1f(v1);
        v2 = v2 > 0.f ? v2 : expm1f(v2);
        v3 = v3 > 0.f ? v3 : expm1f(v3);
        store4(outp, (size_t)wid * 256 + c, make_float4(v0, v1, v2, v3));
    } else {  // mu (c<128) then logstd, each [n,128] fp32, concatenated
        size_t base = (c < 128) ? ((size_t)wid * 128 + c)
                                : ((size_t)n * 128 + (size_t)wid * 128 + (c - 128));
        store4(outp, base, make_float4(v0, v1, v2, v3));
    }
}

// ---------------------------------------------------------------------------
extern "C" void kernel_launch(void* const* d_in, const int* in_sizes, int n_in,
                              void* d_out, int out_size, void* d_ws, size_t ws_size,
                              hipStream_t stream) {
    const float* x = (const float*)d_in[0];
    const u32* ebuf = (const u32*)d_in[1];
    const float* W1 = (const float*)d_in[2];
    const float* a_src1 = (const float*)d_in[3];
    const float* a_dst1 = (const float*)d_in[4];
    const float* b1 = (const float*)d_in[5];
    const float* W_mu = (const float*)d_in[6];
    const float* a_src_mu = (const float*)d_in[7];
    const float* a_dst_mu = (const float*)d_in[8];
    const float* b_mu = (const float*)d_in[9];
    const float* W_ls = (const float*)d_in[10];
    const float* a_src_ls = (const float*)d_in[11];
    const float* a_dst_ls = (const float*)d_in[12];
    const float* b_ls = (const float*)d_in[13];

    const int n = in_sizes[0] / 128;  // 50000
    const int E = in_sizes[1] / 2;    // 800000

    char* base = (char*)d_ws;
    size_t off = 0;
    auto alloc = [&](size_t b) -> char* {
        char* p = base + off;
        off = (off + b + 255) & ~(size_t)255;
        return p;
    };
    int* rowptr = (int*)alloc((size_t)(n + 1) * 4);
    int* cursor = (int*)alloc((size_t)n * 4);
    int* csr = (int*)alloc((size_t)E * 4);
    int* bsum = (int*)alloc(256 * 4);
    int* eflag = (int*)alloc(256);
    int* se = (int*)alloc((size_t)E * 4);
    int* de = (int*)alloc((size_t)E * 4);
    float* as = (float*)alloc((size_t)n * 4 * 4);
    float* ad = (float*)alloc((size_t)n * 4 * 4);
    u16* W1t = (u16*)alloc(256 * 128 * 2);        // W1^T fp16 [256][128]
    u16* Wt2 = (u16*)alloc(256 * 256 * 2);        // [W_mu|W_ls]^T fp16 [256][256]
    u16* x1h = (u16*)alloc((size_t)n * 256 * 2);  // x1 fp16 [n,256]
    u16* xh = x1h;  // alias: xh fp16 [n,128] dead before x1h written
    u16* h = (u16*)alloc((size_t)n * 256 * 2);    // h fp16 (both layers)

    const int nb = (n + 255) / 256;
    const int eg = (E + 255) / 256;
    const int ng4 = (n + 3) / 4;
    const int gg = (n + 63) / 64;

    // edge normalize + CSR build (reused by all three convs)
    hipMemsetAsync(cursor, 0, (size_t)n * 4, stream);
    k_detect<<<1, 256, 0, stream>>>(ebuf, eflag);
    k_extract<<<eg, 256, 0, stream>>>(ebuf, E, eflag, se, de, cursor);
    k_scan_a<<<nb, 256, 0, stream>>>(cursor, n, bsum);
    k_scan_b<<<1, 256, 0, stream>>>(bsum, nb);
    k_scan_c<<<nb, 256, 0, stream>>>(cursor, n, bsum, rowptr, cursor, E);
    k_fill<<<eg, 256, 0, stream>>>(se, de, E, cursor, csr);

    // fp16 conversions / weight transposes
    k_cvt<<<(n * 128 / 4 + 255) / 256, 256, 0, stream>>>(x, xh, n * 128);
    k_tw<<<(256 * 128 + 255) / 256, 256, 0, stream>>>(W1, W1, 256, 128, W1t);
    k_tw<<<(256 * 256 + 255) / 256, 256, 0, stream>>>(W_mu, W_ls, 128, 256, Wt2);

    // Layer 1: h = x@W1 (MFMA, fused alphas); aggregate -> ELU -> x1 (fp16)
    k_gemm_mfma<128, 5><<<gg, 256, 0, stream>>>(xh, W1t, h, as, ad, a_src1,
                                                a_src1 + 128, a_dst1, a_dst1 + 128,
                                                n);
    k_agg<5, 0, u16><<<ng4, 256, 0, stream>>>(h, rowptr, csr, as, ad, b1, b1 + 128,
                                              x1h, n);

    // Layers mu & ls: h = x1@[W_mu|W_ls] (MFMA, fused alphas); aggregate
    k_gemm_mfma<256, 4><<<gg, 256, 0, stream>>>(x1h, Wt2, h, as, ad, a_src_mu,
                                                a_src_ls, a_dst_mu, a_dst_ls, n);
    k_agg<4, 1, float><<<ng4, 256, 0, stream>>>(h, rowptr, csr, as, ad, b_mu, b_ls,
                                                (float*)d_out, n);
}